// Round 5
// baseline (120.751 us; speedup 1.0000x reference)
//
#include <hip/hip_runtime.h>

// TropicalLeNet fused, one 1024-thread block per image.
// R5: FC1/FC2 weights prefetched into VGPRs right after staging so the
// ~192KB/CU L2 read overlaps the conv VALU phases; FC1 computes 2 outputs
// per thread from one x-slice (halves FC1 LDS reads). Convs as in R4.

#define POS_INF 1e30f

__global__ __launch_bounds__(1024) void lenet_fused(
    const float* __restrict__ input,  // [256,1,28,28]
    const float* __restrict__ w1,     // [6,1,5,5]
    const float* __restrict__ w2,     // [16,6,5,5]
    const float* __restrict__ fw1,    // [120,400]
    const float* __restrict__ fb1,    // [120]
    const float* __restrict__ fw2,    // [84,120]
    const float* __restrict__ fb2,    // [84]
    const float* __restrict__ fw3,    // [10,84]
    const float* __restrict__ fb3,    // [10]
    float* __restrict__ out)          // [256,10]
{
    // ---- LDS arena: 15760 floats = 63.04 KB ----
    __shared__ float smem[15760];
    float* sW1p = smem;           // w1 padded stride 28 (176)
    float* sW2p = smem + 176;     // w2 padded stride 28 (2688)
    float* sX1c = smem + 2864;    // 2 shifted copies [2][6][14][16] = 2688
    float* sX2  = smem + 5552;    // 400
    float* sH1  = smem + 5952;    // 120
    float* sH2  = smem + 6072;    // 84 (pad 88)
    float* A    = smem + 6160;    // 9600-float union
    float* sIn  = A;              // [2][32][32] shifted padded input (phase 1)
    float* sP2  = A;              // [16*6][10][10] conv2 prepool (phase 2)

    const int tid = threadIdx.x;
    const int b = blockIdx.x;

    // ---- stage: padded weights + 2 shifted copies of zero-padded input ----
    if (tid < 150) sW1p[(tid / 25) * 28 + tid % 25] = w1[tid];
    for (int i = tid; i < 2400; i += 1024)
        sW2p[(i / 25) * 28 + (i % 25)] = w2[i];
    {
        int r = tid >> 5, cc = tid & 31;
        const float* inb = input + b * 784;
        float v0 = 0.f, v1 = 0.f;
        if (r >= 2 && r < 30) {
            if (cc >= 2 && cc < 30) v0 = inb[(r - 2) * 28 + (cc - 2)]; // shift 0
            if (cc < 28)            v1 = inb[(r - 2) * 28 + cc];       // shift 2
        }
        sIn[tid] = v0;          // copy0[c] = xpad[c]
        sIn[1024 + tid] = v1;   // copy1[c] = xpad[c+2]
    }
    __syncthreads();

    // ---- FC weight prefetch into VGPRs (overlaps conv phases; plain
    // global->VGPR loads stay in flight across s_barrier) ----
    float4 wA[13], wB[13];
    float biasA = 0.f, biasB = 0.f;
    if (tid < 480) {
        const int n2 = tid >> 3, s8 = tid & 7;
        const float4* r0 = (const float4*)(fw1 + n2 * 400);
        const float4* r1 = (const float4*)(fw1 + (n2 + 60) * 400);
        #pragma unroll
        for (int i = 0; i < 12; ++i) {
            wA[i] = r0[s8 + 8 * i];
            wB[i] = r1[s8 + 8 * i];
        }
        if (s8 < 4) { wA[12] = r0[96 + s8]; wB[12] = r1[96 + s8]; }
        biasA = fb1[n2]; biasB = fb1[n2 + 60];
    }
    float2 wC[15];
    float biasC = 0.f;
    if (tid < 336) {
        const int n = tid >> 2, s4 = tid & 3;
        const float2* r = (const float2*)(fw2 + n * 120);
        #pragma unroll
        for (int i = 0; i < 15; ++i) wC[i] = r[s4 * 15 + i];
        biasC = fb2[n];
    }

    // ---- conv1 (min-plus, pad=2) + pool1 fused: (o<6, g<7, jp<14) = 588 thr ----
    if (tid < 588) {
        int o = tid / 98, rem = tid % 98;
        int g = rem / 14, jp = rem % 14;
        const int J = 2 * jp;
        const int s = J & 3;                    // 0 or 2
        const float* xbase = sIn + (s >> 1) * 1024 + (J - s);
        float w[25];
        #pragma unroll
        for (int q = 0; q < 6; ++q) {
            float4 t = ((const float4*)(sW1p + o * 28))[q];
            w[4*q] = t.x; w[4*q+1] = t.y; w[4*q+2] = t.z; w[4*q+3] = t.w;
        }
        w[24] = sW1p[o * 28 + 24];
        float accA[4], accB[4];
        #pragma unroll
        for (int h = 0; h < 4; ++h) { accA[h] = POS_INF; accB[h] = POS_INF; }
        #pragma unroll
        for (int ir = 0; ir < 8; ++ir) {        // input rows 4g+ir
            const float* row = xbase + (4 * g + ir) * 32;
            float4 xa = ((const float4*)row)[0];
            float4 xb = ((const float4*)row)[1];
            float x[8] = {xa.x, xa.y, xa.z, xa.w, xb.x, xb.y, xb.z, xb.w};
            #pragma unroll
            for (int h = 0; h < 4; ++h) {
                if (ir >= h && ir <= h + 4) {   // compile-time pruned
                    const int i = ir - h;
                    #pragma unroll
                    for (int j = 0; j < 5; ++j) {
                        accA[h] = fminf(accA[h], x[j]     + w[i*5+j]);
                        accB[h] = fminf(accB[h], x[j + 1] + w[i*5+j]);
                    }
                }
            }
        }
        float p0 = 0.25f * (accA[0] + accB[0] + accA[1] + accB[1]);
        float p1 = 0.25f * (accA[2] + accB[2] + accA[3] + accB[3]);
        #pragma unroll
        for (int ci = 0; ci < 2; ++ci) {
            int col = jp - 2 * ci;
            if (col >= 0) {
                float* dst = sX1c + ci * 1344 + o * 224 + (2 * g) * 16 + col;
                dst[0]  = p0;   // pooled row 2g
                dst[16] = p1;   // pooled row 2g+1
            }
        }
    }
    __syncthreads();

    // ---- conv2 prepool (max-plus): (o2<8, c<6, jp<5, half<2) = 480 thr ----
    if (tid < 480) {
        int o2 = tid / 60, rem = tid % 60;
        int c = rem / 10, r2 = rem % 10;
        int jp = r2 >> 1, half = r2 & 1;
        const int j0 = 2 * jp;                  // 0,2,4,6,8
        const int s = j0 & 3;                   // 0 or 2
        const int h0 = 5 * half;
        const int oa = 2 * o2;
        float wa[25], wb[25];
        #pragma unroll
        for (int q = 0; q < 6; ++q) {
            float4 t = ((const float4*)(sW2p + (oa * 6 + c) * 28))[q];
            wa[4*q] = t.x; wa[4*q+1] = t.y; wa[4*q+2] = t.z; wa[4*q+3] = t.w;
            float4 u = ((const float4*)(sW2p + ((oa + 1) * 6 + c) * 28))[q];
            wb[4*q] = u.x; wb[4*q+1] = u.y; wb[4*q+2] = u.z; wb[4*q+3] = u.w;
        }
        wa[24] = sW2p[(oa * 6 + c) * 28 + 24];
        wb[24] = sW2p[((oa + 1) * 6 + c) * 28 + 24];
        float aa0[5], aa1[5], ab0[5], ab1[5];
        #pragma unroll
        for (int h = 0; h < 5; ++h) {
            aa0[h] = -POS_INF; aa1[h] = -POS_INF;
            ab0[h] = -POS_INF; ab1[h] = -POS_INF;
        }
        const float* xbase = sX1c + (s >> 1) * 1344 + c * 224 + (j0 - s);
        #pragma unroll
        for (int r = 0; r < 9; ++r) {           // input rows h0+r
            const float* row = xbase + (h0 + r) * 16;
            float4 xa = ((const float4*)row)[0];
            float4 xb = ((const float4*)row)[1];
            float x[8] = {xa.x, xa.y, xa.z, xa.w, xb.x, xb.y, xb.z, xb.w};
            #pragma unroll
            for (int h = 0; h < 5; ++h) {
                if (r >= h && r <= h + 4) {     // compile-time pruned
                    const int i = r - h;
                    #pragma unroll
                    for (int j = 0; j < 5; ++j) {
                        const float va = wa[i*5+j], vb = wb[i*5+j];
                        aa0[h] = fmaxf(aa0[h], x[j]     + va);
                        aa1[h] = fmaxf(aa1[h], x[j + 1] + va);
                        ab0[h] = fmaxf(ab0[h], x[j]     + vb);
                        ab1[h] = fmaxf(ab1[h], x[j + 1] + vb);
                    }
                }
            }
        }
        float* da = sP2 + (oa * 6 + c) * 100 + j0;
        float* db = sP2 + ((oa + 1) * 6 + c) * 100 + j0;
        #pragma unroll
        for (int h = 0; h < 5; ++h) {
            da[(h0 + h) * 10]     = aa0[h];
            da[(h0 + h) * 10 + 1] = aa1[h];
            db[(h0 + h) * 10]     = ab0[h];
            db[(h0 + h) * 10 + 1] = ab1[h];
        }
    }
    __syncthreads();

    // ---- pool2 + channel sum -> sX2[400] (flat [16][5][5]) ----
    if (tid < 400) {
        int o = tid / 25, rem = tid % 25, ph = rem / 5, pw = rem % 5;
        float s = 0.f;
        #pragma unroll
        for (int c = 0; c < 6; ++c) {
            const float* p = sP2 + (o * 6 + c) * 100 + 2 * ph * 10 + 2 * pw;
            float2 u = *(const float2*)p;
            float2 v = *(const float2*)(p + 10);
            s += u.x + u.y + v.x + v.y;
        }
        sX2[tid] = 0.25f * s;
    }
    __syncthreads();

    // ---- FC1: 60 output-pairs x 8-way float4 split (480 thr), shfl reduce ----
    if (tid < 480) {
        const int n2 = tid >> 3, s8 = tid & 7;
        const float4* xv = (const float4*)sX2;
        float a = 0.f, c = 0.f;
        #pragma unroll
        for (int i = 0; i < 12; ++i) {
            float4 x4 = xv[s8 + 8 * i];
            a += wA[i].x*x4.x + wA[i].y*x4.y + wA[i].z*x4.z + wA[i].w*x4.w;
            c += wB[i].x*x4.x + wB[i].y*x4.y + wB[i].z*x4.z + wB[i].w*x4.w;
        }
        if (s8 < 4) {
            float4 x4 = xv[96 + s8];
            a += wA[12].x*x4.x + wA[12].y*x4.y + wA[12].z*x4.z + wA[12].w*x4.w;
            c += wB[12].x*x4.x + wB[12].y*x4.y + wB[12].z*x4.z + wB[12].w*x4.w;
        }
        a += __shfl_xor(a, 1, 8); a += __shfl_xor(a, 2, 8); a += __shfl_xor(a, 4, 8);
        c += __shfl_xor(c, 1, 8); c += __shfl_xor(c, 2, 8); c += __shfl_xor(c, 4, 8);
        if (s8 == 0) {
            sH1[n2]      = fmaxf(a + biasA, 0.f);
            sH1[n2 + 60] = fmaxf(c + biasB, 0.f);
        }
    }
    __syncthreads();

    // ---- FC2: 84 x 4-way float2 split (336 thr), prefetched weights ----
    if (tid < 336) {
        const int n = tid >> 2, s4 = tid & 3;
        const float2* xv2 = (const float2*)sH1;
        float a = 0.f;
        #pragma unroll
        for (int i = 0; i < 15; ++i) {
            float2 x2 = xv2[s4 * 15 + i];
            a += wC[i].x * x2.x + wC[i].y * x2.y;
        }
        a += __shfl_xor(a, 1, 4); a += __shfl_xor(a, 2, 4);
        if (s4 == 0) sH2[n] = fmaxf(a + biasC, 0.f);
    }
    __syncthreads();

    // ---- FC3: 10 x 4-way K-split (40 thr), shfl reduce ----
    if (tid < 40) {
        int n = tid >> 2, s4 = tid & 3;
        const float* w = fw3 + n * 84 + s4 * 21;
        const float* x = sH2 + s4 * 21;
        float a = 0.f;
        #pragma unroll 7
        for (int k = 0; k < 21; ++k) a += x[k] * w[k];
        a += __shfl_xor(a, 1, 4);
        a += __shfl_xor(a, 2, 4);
        if (s4 == 0) out[b * 10 + n] = a + fb3[n];
    }
}

extern "C" void kernel_launch(void* const* d_in, const int* in_sizes, int n_in,
                              void* d_out, int out_size, void* d_ws, size_t ws_size,
                              hipStream_t stream) {
    const float* input = (const float*)d_in[0];
    const float* w1  = (const float*)d_in[1];
    const float* w2  = (const float*)d_in[2];
    const float* fw1 = (const float*)d_in[3];
    const float* fb1 = (const float*)d_in[4];
    const float* fw2 = (const float*)d_in[5];
    const float* fb2 = (const float*)d_in[6];
    const float* fw3 = (const float*)d_in[7];
    const float* fb3 = (const float*)d_in[8];
    float* out = (float*)d_out;

    lenet_fused<<<256, 1024, 0, stream>>>(input, w1, w2, fw1, fb1, fw2, fb2,
                                          fw3, fb3, out);
}

// Round 6
// 79.899 us; speedup vs baseline: 1.5113x; 1.5113x over previous
//
#include <hip/hip_runtime.h>

// TropicalLeNet fused, one 1024-thread block per image.
// R6 = R4 (proven 79.2us) + FC1 two-outputs-per-thread (halves FC1 LDS reads,
// weights streamed in-loop -> no cross-phase register residency, no spill).
// R5 lesson: launch_bounds(1024) => 64-VGPR budget; holding ~134 floats across
// barriers spilled to scratch (148MB WRITE_SIZE/dispatch, 62us). Never again.

#define POS_INF 1e30f

__global__ __launch_bounds__(1024) void lenet_fused(
    const float* __restrict__ input,  // [256,1,28,28]
    const float* __restrict__ w1,     // [6,1,5,5]
    const float* __restrict__ w2,     // [16,6,5,5]
    const float* __restrict__ fw1,    // [120,400]
    const float* __restrict__ fb1,    // [120]
    const float* __restrict__ fw2,    // [84,120]
    const float* __restrict__ fb2,    // [84]
    const float* __restrict__ fw3,    // [10,84]
    const float* __restrict__ fb3,    // [10]
    float* __restrict__ out)          // [256,10]
{
    // ---- LDS arena: 15760 floats = 63.04 KB ----
    __shared__ float smem[15760];
    float* sW1p = smem;           // w1 padded stride 28 (176)
    float* sW2p = smem + 176;     // w2 padded stride 28 (2688)
    float* sX1c = smem + 2864;    // 2 shifted copies [2][6][14][16] = 2688
    float* sX2  = smem + 5552;    // 400
    float* sH1  = smem + 5952;    // 120
    float* sH2  = smem + 6072;    // 84 (pad 88)
    float* A    = smem + 6160;    // 9600-float union
    float* sIn  = A;              // [2][32][32] shifted padded input (phase 1)
    float* sP2  = A;              // [16*6][10][10] conv2 prepool (phase 2)

    const int tid = threadIdx.x;
    const int b = blockIdx.x;

    // ---- stage: padded weights + 2 shifted copies of zero-padded input ----
    if (tid < 150) sW1p[(tid / 25) * 28 + tid % 25] = w1[tid];
    for (int i = tid; i < 2400; i += 1024)
        sW2p[(i / 25) * 28 + (i % 25)] = w2[i];
    {
        int r = tid >> 5, cc = tid & 31;
        const float* inb = input + b * 784;
        float v0 = 0.f, v1 = 0.f;
        if (r >= 2 && r < 30) {
            if (cc >= 2 && cc < 30) v0 = inb[(r - 2) * 28 + (cc - 2)]; // shift 0
            if (cc < 28)            v1 = inb[(r - 2) * 28 + cc];       // shift 2
        }
        sIn[tid] = v0;          // copy0[c] = xpad[c]
        sIn[1024 + tid] = v1;   // copy1[c] = xpad[c+2]
    }
    __syncthreads();

    // ---- conv1 (min-plus, pad=2) + pool1 fused: (o<6, g<7, jp<14) = 588 thr ----
    if (tid < 588) {
        int o = tid / 98, rem = tid % 98;
        int g = rem / 14, jp = rem % 14;
        const int J = 2 * jp;
        const int s = J & 3;                    // 0 or 2
        const float* xbase = sIn + (s >> 1) * 1024 + (J - s);
        float w[25];
        #pragma unroll
        for (int q = 0; q < 6; ++q) {
            float4 t = ((const float4*)(sW1p + o * 28))[q];
            w[4*q] = t.x; w[4*q+1] = t.y; w[4*q+2] = t.z; w[4*q+3] = t.w;
        }
        w[24] = sW1p[o * 28 + 24];
        float accA[4], accB[4];
        #pragma unroll
        for (int h = 0; h < 4; ++h) { accA[h] = POS_INF; accB[h] = POS_INF; }
        #pragma unroll
        for (int ir = 0; ir < 8; ++ir) {        // input rows 4g+ir
            const float* row = xbase + (4 * g + ir) * 32;
            float4 xa = ((const float4*)row)[0];
            float4 xb = ((const float4*)row)[1];
            float x[8] = {xa.x, xa.y, xa.z, xa.w, xb.x, xb.y, xb.z, xb.w};
            #pragma unroll
            for (int h = 0; h < 4; ++h) {
                if (ir >= h && ir <= h + 4) {   // compile-time pruned
                    const int i = ir - h;
                    #pragma unroll
                    for (int j = 0; j < 5; ++j) {
                        accA[h] = fminf(accA[h], x[j]     + w[i*5+j]);
                        accB[h] = fminf(accB[h], x[j + 1] + w[i*5+j]);
                    }
                }
            }
        }
        float p0 = 0.25f * (accA[0] + accB[0] + accA[1] + accB[1]);
        float p1 = 0.25f * (accA[2] + accB[2] + accA[3] + accB[3]);
        #pragma unroll
        for (int ci = 0; ci < 2; ++ci) {
            int col = jp - 2 * ci;
            if (col >= 0) {
                float* dst = sX1c + ci * 1344 + o * 224 + (2 * g) * 16 + col;
                dst[0]  = p0;   // pooled row 2g
                dst[16] = p1;   // pooled row 2g+1
            }
        }
    }
    __syncthreads();

    // ---- conv2 prepool (max-plus): (o2<8, c<6, jp<5, half<2) = 480 thr ----
    if (tid < 480) {
        int o2 = tid / 60, rem = tid % 60;
        int c = rem / 10, r2 = rem % 10;
        int jp = r2 >> 1, half = r2 & 1;
        const int j0 = 2 * jp;                  // 0,2,4,6,8
        const int s = j0 & 3;                   // 0 or 2
        const int h0 = 5 * half;
        const int oa = 2 * o2;
        float wa[25], wb[25];
        #pragma unroll
        for (int q = 0; q < 6; ++q) {
            float4 t = ((const float4*)(sW2p + (oa * 6 + c) * 28))[q];
            wa[4*q] = t.x; wa[4*q+1] = t.y; wa[4*q+2] = t.z; wa[4*q+3] = t.w;
            float4 u = ((const float4*)(sW2p + ((oa + 1) * 6 + c) * 28))[q];
            wb[4*q] = u.x; wb[4*q+1] = u.y; wb[4*q+2] = u.z; wb[4*q+3] = u.w;
        }
        wa[24] = sW2p[(oa * 6 + c) * 28 + 24];
        wb[24] = sW2p[((oa + 1) * 6 + c) * 28 + 24];
        float aa0[5], aa1[5], ab0[5], ab1[5];
        #pragma unroll
        for (int h = 0; h < 5; ++h) {
            aa0[h] = -POS_INF; aa1[h] = -POS_INF;
            ab0[h] = -POS_INF; ab1[h] = -POS_INF;
        }
        const float* xbase = sX1c + (s >> 1) * 1344 + c * 224 + (j0 - s);
        #pragma unroll
        for (int r = 0; r < 9; ++r) {           // input rows h0+r
            const float* row = xbase + (h0 + r) * 16;
            float4 xa = ((const float4*)row)[0];
            float4 xb = ((const float4*)row)[1];
            float x[8] = {xa.x, xa.y, xa.z, xa.w, xb.x, xb.y, xb.z, xb.w};
            #pragma unroll
            for (int h = 0; h < 5; ++h) {
                if (r >= h && r <= h + 4) {     // compile-time pruned
                    const int i = r - h;
                    #pragma unroll
                    for (int j = 0; j < 5; ++j) {
                        const float va = wa[i*5+j], vb = wb[i*5+j];
                        aa0[h] = fmaxf(aa0[h], x[j]     + va);
                        aa1[h] = fmaxf(aa1[h], x[j + 1] + va);
                        ab0[h] = fmaxf(ab0[h], x[j]     + vb);
                        ab1[h] = fmaxf(ab1[h], x[j + 1] + vb);
                    }
                }
            }
        }
        float* da = sP2 + (oa * 6 + c) * 100 + j0;
        float* db = sP2 + ((oa + 1) * 6 + c) * 100 + j0;
        #pragma unroll
        for (int h = 0; h < 5; ++h) {
            da[(h0 + h) * 10]     = aa0[h];
            da[(h0 + h) * 10 + 1] = aa1[h];
            db[(h0 + h) * 10]     = ab0[h];
            db[(h0 + h) * 10 + 1] = ab1[h];
        }
    }
    __syncthreads();

    // ---- pool2 + channel sum -> sX2[400] (flat [16][5][5]) ----
    if (tid < 400) {
        int o = tid / 25, rem = tid % 25, ph = rem / 5, pw = rem % 5;
        float s = 0.f;
        #pragma unroll
        for (int c = 0; c < 6; ++c) {
            const float* p = sP2 + (o * 6 + c) * 100 + 2 * ph * 10 + 2 * pw;
            float2 u = *(const float2*)p;
            float2 v = *(const float2*)(p + 10);
            s += u.x + u.y + v.x + v.y;
        }
        sX2[tid] = 0.25f * s;
    }
    __syncthreads();

    // ---- FC1: 60 output-pairs x 8-way float4 split (480 thr), shfl reduce ----
    // Weights streamed from global IN-LOOP (no cross-phase residency).
    if (tid < 480) {
        const int n2 = tid >> 3, s8 = tid & 7;
        const float4* r0 = (const float4*)(fw1 + n2 * 400);
        const float4* r1 = (const float4*)(fw1 + (n2 + 60) * 400);
        const float4* xv = (const float4*)sX2;
        float a = 0.f, c = 0.f;
        #pragma unroll
        for (int i = 0; i < 12; ++i) {
            const int j = s8 + 8 * i;
            float4 x4 = xv[j];
            float4 wv = r0[j];
            float4 wu = r1[j];
            a += wv.x*x4.x + wv.y*x4.y + wv.z*x4.z + wv.w*x4.w;
            c += wu.x*x4.x + wu.y*x4.y + wu.z*x4.z + wu.w*x4.w;
        }
        if (s8 < 4) {
            const int j = 96 + s8;
            float4 x4 = xv[j];
            float4 wv = r0[j];
            float4 wu = r1[j];
            a += wv.x*x4.x + wv.y*x4.y + wv.z*x4.z + wv.w*x4.w;
            c += wu.x*x4.x + wu.y*x4.y + wu.z*x4.z + wu.w*x4.w;
        }
        a += __shfl_xor(a, 1, 8); a += __shfl_xor(a, 2, 8); a += __shfl_xor(a, 4, 8);
        c += __shfl_xor(c, 1, 8); c += __shfl_xor(c, 2, 8); c += __shfl_xor(c, 4, 8);
        if (s8 == 0) {
            sH1[n2]      = fmaxf(a + fb1[n2], 0.f);
            sH1[n2 + 60] = fmaxf(c + fb1[n2 + 60], 0.f);
        }
    }
    __syncthreads();

    // ---- FC2: 84 x 2-way float4-split (168 thr), shfl reduce ----
    if (tid < 168) {
        int n = tid >> 1, s2 = tid & 1;
        const float4* wrow = (const float4*)(fw2 + n * 120);
        const float4* xv = (const float4*)sH1;
        float a = 0.f;
        #pragma unroll
        for (int i = 0; i < 15; ++i) {
            int j = s2 + 2 * i;
            float4 wv = wrow[j];
            float4 x4 = xv[j];
            a += wv.x * x4.x + wv.y * x4.y + wv.z * x4.z + wv.w * x4.w;
        }
        a += __shfl_xor(a, 1, 2);
        if (s2 == 0) sH2[n] = fmaxf(a + fb2[n], 0.f);
    }
    __syncthreads();

    // ---- FC3: 10 x 4-way K-split (40 thr), shfl reduce ----
    if (tid < 40) {
        int n = tid >> 2, s4 = tid & 3;
        const float* w = fw3 + n * 84 + s4 * 21;
        const float* x = sH2 + s4 * 21;
        float a = 0.f;
        #pragma unroll 7
        for (int k = 0; k < 21; ++k) a += x[k] * w[k];
        a += __shfl_xor(a, 1, 4);
        a += __shfl_xor(a, 2, 4);
        if (s4 == 0) out[b * 10 + n] = a + fb3[n];
    }
}

extern "C" void kernel_launch(void* const* d_in, const int* in_sizes, int n_in,
                              void* d_out, int out_size, void* d_ws, size_t ws_size,
                              hipStream_t stream) {
    const float* input = (const float*)d_in[0];
    const float* w1  = (const float*)d_in[1];
    const float* w2  = (const float*)d_in[2];
    const float* fw1 = (const float*)d_in[3];
    const float* fb1 = (const float*)d_in[4];
    const float* fw2 = (const float*)d_in[5];
    const float* fb2 = (const float*)d_in[6];
    const float* fw3 = (const float*)d_in[7];
    const float* fb3 = (const float*)d_in[8];
    float* out = (float*)d_out;

    lenet_fused<<<256, 1024, 0, stream>>>(input, w1, w2, fw1, fb1, fw2, fb2,
                                          fw3, fb3, out);
}